// Round 17
// baseline (306.019 us; speedup 1.0000x reference)
//
#include <hip/hip_runtime.h>
#include <hip/hip_fp16.h>

// 2-layer GCN: out = gcn(relu(gcn(x,W1,b1,e0)), W2, b2, e1)
// Lessons: no device-scope atomics (R2/R10); write-amp 1.0 via LDS chunk
//   sort + coalesced writeout (R5); pull agg + many blocks for latency
//   hiding (R7); registers beat LDS for pass-to-pass data (R9).
// R14: agg 55.3us (16 lanes/edge, 8-gather rounds) -- PROVEN FLOOR:
//   85% BW-bound on the L2-miss path (FETCH 160MB @3.4TB/s = 47/55.5us).
// R16: bfin4 LDS cut: -2.8us (DS-issue-bound). R19/R20: bsum+transpose
//   deleted via identities. R21/R22: CHUNK 8192. R24: reverted slab,
//   303.5us BEST (agg 56.1/160MB reproduced).
// R17/R18/R23 slab-agg family: CONDEMNED (FETCH drops 160->54MB as
//   predicted but payload-slicing multiplies round count x4; time
//   regresses 133/88/84.5). FETCH necessary, not sufficient.
// R25: L2 stream-pollution theory: csr (single-use) + out (no reuse)
//   streams evict H lines (~12 future uses each). Mark both NON-TEMPORAL.
//   Predict FETCH 160->135-150, agg 56->49-53; FETCH unchanged -> H hit
//   rate capacity-limited -> ROOFLINE at ~303.
// R26: compile fix only -- __builtin_nontemporal_store rejects HIP
//   float4 (struct-wrapped); use native ext_vector_type(4) float.

#define NPB   128
#define BSH   7
#define BMSK  127
#define MAXB  1024          // >= B = ceil(100000/128) = 782
#define ROST  (MAXB + 1)    // runoff row stride
#define CHUNK 8192
#define EPTH  32            // edges per thread = CHUNK/256
#define MAXCH 512           // >= nchunk = ceil(E/CHUNK) = 391
#define BCAP  5120          // bucket cap (mean 4096, sd 64 -> +16sd)
#define GPT   20            // gather regs per thread = BCAP/256

typedef float nfloat4 __attribute__((ext_vector_type(4)));

// Sort chunk k by dst-bucket; edge data held in REGISTERS between passes.
// Dual-set: blockIdx.y selects layer (A=0, B=1).
__global__ __launch_bounds__(256) void k_scatter(const int* srcA, const int* dstA,
                                                 int* runA, int* pkA,
                                                 const int* srcB, const int* dstB,
                                                 int* runB, int* pkB,
                                                 int E, int B) {
  const int* src = blockIdx.y ? srcB : srcA;
  const int* dst = blockIdx.y ? dstB : dstA;
  int* runoff = blockIdx.y ? runB : runA;
  int* packed = blockIdx.y ? pkB : pkA;
  __shared__ int sorted[CHUNK];
  __shared__ int hist[MAXB];
  __shared__ int wsum[4];
  int t = threadIdx.x;
  int k = blockIdx.x;
  int e0 = k * CHUNK;
  int cnt = min(CHUNK, E - e0);
  for (int b = t; b < B; b += 256) hist[b] = 0;
  __syncthreads();
  int pk[EPTH];
  int bk[EPTH];
  int base = t * EPTH;
  int nloc = min(EPTH, max(0, cnt - base));
  if (cnt == CHUNK) {
    const int4* s4 = (const int4*)(src + e0 + base);
    const int4* d4 = (const int4*)(dst + e0 + base);
#pragma unroll
    for (int g = 0; g < EPTH / 4; ++g) {
      int4 sv = s4[g];
      int4 dv = d4[g];
      pk[4 * g + 0] = (sv.x << BSH) | (dv.x & BMSK); bk[4 * g + 0] = dv.x >> BSH;
      pk[4 * g + 1] = (sv.y << BSH) | (dv.y & BMSK); bk[4 * g + 1] = dv.y >> BSH;
      pk[4 * g + 2] = (sv.z << BSH) | (dv.z & BMSK); bk[4 * g + 2] = dv.z >> BSH;
      pk[4 * g + 3] = (sv.w << BSH) | (dv.w & BMSK); bk[4 * g + 3] = dv.w >> BSH;
      atomicAdd(&hist[bk[4 * g + 0]], 1);
      atomicAdd(&hist[bk[4 * g + 1]], 1);
      atomicAdd(&hist[bk[4 * g + 2]], 1);
      atomicAdd(&hist[bk[4 * g + 3]], 1);
    }
  } else {
    for (int q = 0; q < nloc; ++q) {
      int d = dst[e0 + base + q], s = src[e0 + base + q];
      pk[q] = (s << BSH) | (d & BMSK);
      bk[q] = d >> BSH;
      atomicAdd(&hist[bk[q]], 1);
    }
  }
  __syncthreads();
  int i0 = t * 4;
  int v0 = (i0 + 0 < B) ? hist[i0 + 0] : 0;
  int v1 = (i0 + 1 < B) ? hist[i0 + 1] : 0;
  int v2 = (i0 + 2 < B) ? hist[i0 + 2] : 0;
  int v3 = (i0 + 3 < B) ? hist[i0 + 3] : 0;
  int tsum = v0 + v1 + v2 + v3;
  int lane = t & 63, wid = t >> 6;
  int x = tsum;
#pragma unroll
  for (int d = 1; d < 64; d <<= 1) {
    int y = __shfl_up(x, d, 64);
    if (lane >= d) x += y;
  }
  if (lane == 63) wsum[wid] = x;
  __syncthreads();
  int wofs = 0;
  for (int ww = 0; ww < wid; ++ww) wofs += wsum[ww];
  int excl = wofs + x - tsum;
  hist[i0 + 0] = excl;
  hist[i0 + 1] = excl + v0;
  hist[i0 + 2] = excl + v0 + v1;
  hist[i0 + 3] = excl + v0 + v1 + v2;
  __syncthreads();
  int* row = runoff + (size_t)k * ROST;
  for (int b = t; b < B; b += 256) row[b] = hist[b];
  if (t == 0) row[B] = cnt;
  __syncthreads();
#pragma unroll
  for (int q = 0; q < EPTH; ++q) {
    if (q < nloc) {
      int pos = atomicAdd(&hist[bk[q]], 1);
      sorted[pos] = pk[q];
    }
  }
  __syncthreads();
  if (cnt == CHUNK) {
    int4* po = (int4*)(packed + e0 + base);
    const int4* so = (const int4*)(sorted + base);
#pragma unroll
    for (int g = 0; g < EPTH / 4; ++g) po[g] = so[g];
  } else {
    for (int i = t; i < cnt; i += 256) packed[e0 + i] = sorted[i];
  }
}

// Per-bucket finalize. Reads runoff directly (R20); wbase = column-sum
// of s (R19 identity); registers carry edges between passes (R16);
// guarded pref stores (R22).
__global__ __launch_bounds__(256) void k_bfin4(const int* pkA, const int* runA,
                                               int* offA, float* dinvA, int* csrA,
                                               const int* pkB, const int* runB,
                                               int* offB, float* dinvB, int* csrB,
                                               int N, int B, int nchunk, int E) {
  int l = blockIdx.y;
  const int* packed = l ? pkB : pkA;
  const int* runoff = l ? runB : runA;
  int* off = l ? offB : offA;
  float* dinv = l ? dinvB : dinvA;
  int* csr = l ? csrB : csrA;
  __shared__ int rs[MAXCH];
  __shared__ unsigned short rl[MAXCH];
  __shared__ int pref[MAXCH];
  __shared__ int slot[BCAP];
  __shared__ int cntL[NPB];
  __shared__ int curL[NPB];
  __shared__ int wsum[4];
  __shared__ int rsum[4];
  int t = threadIdx.x;
  int b = blockIdx.x;
  int lane = t & 63, w = t >> 6;
  int psS = 0;  // partial column-sum of s-values -> wbase
  for (int k = t; k < nchunk; k += 256) {
    const int* row = runoff + (size_t)k * ROST + b;
    int s = row[0];
    int e = row[1];
    rs[k] = k * CHUNK + s;
    rl[k] = (unsigned short)(e - s);
    psS += s;
  }
  if (t < NPB) cntL[t] = 0;
#pragma unroll
  for (int d = 32; d >= 1; d >>= 1) psS += __shfl_down(psS, d, 64);
  if (lane == 0) rsum[w] = psS;
  __syncthreads();
  int wbase = rsum[0] + rsum[1] + rsum[2] + rsum[3];
  int i0 = t * 4;
  int v0 = (i0 + 0 < nchunk) ? rl[i0 + 0] : 0;
  int v1 = (i0 + 1 < nchunk) ? rl[i0 + 1] : 0;
  int v2 = (i0 + 2 < nchunk) ? rl[i0 + 2] : 0;
  int v3 = (i0 + 3 < nchunk) ? rl[i0 + 3] : 0;
  int tsum = v0 + v1 + v2 + v3;
  int x = tsum;
#pragma unroll
  for (int d = 1; d < 64; d <<= 1) {
    int y = __shfl_up(x, d, 64);
    if (lane >= d) x += y;
  }
  if (lane == 63) wsum[w] = x;
  __syncthreads();
  int total = wsum[0] + wsum[1] + wsum[2] + wsum[3];
  int wofs = 0;
  for (int ww = 0; ww < w; ++ww) wofs += wsum[ww];
  int excl = wofs + x - tsum;
  if (i0 < MAXCH) {  // R22 fix: guard LDS stores
    pref[i0 + 0] = excl;
    pref[i0 + 1] = excl + v0;
    pref[i0 + 2] = excl + v0 + v1;
    pref[i0 + 3] = excl + v0 + v1 + v2;
  }
  __syncthreads();
  bool inLDS = (total <= BCAP);
  int ev[GPT];
  if (inLDS) {
    for (int k = t; k < nchunk; k += 256) {
      int base = rs[k], len = rl[k], o = pref[k];
      for (int j = 0; j < len; ++j) slot[o + j] = base + j;
    }
    __syncthreads();
    int av[GPT];
#pragma unroll
    for (int g = 0; g < GPT; ++g) {
      int i = t + g * 256;
      av[g] = (i < total) ? slot[i] : -1;
    }
#pragma unroll
    for (int g = 0; g < GPT; ++g) ev[g] = (av[g] >= 0) ? packed[av[g]] : 0;
#pragma unroll
    for (int g = 0; g < GPT; ++g) {
      int i = t + g * 256;
      if (i < total) atomicAdd(&cntL[ev[g] & BMSK], 1);
    }
  } else {
    for (int k = t; k < nchunk; k += 256) {
      int base = rs[k], len = rl[k];
      for (int j = 0; j < len; ++j)
        atomicAdd(&cntL[packed[base + j] & BMSK], 1);
    }
  }
  __syncthreads();
  int c = (t < NPB) ? cntL[t] : 0;
  x = c;
#pragma unroll
  for (int d = 1; d < 64; d <<= 1) {
    int y = __shfl_up(x, d, 64);
    if (lane >= d) x += y;
  }
  if (lane == 63) wsum[w] = x;
  __syncthreads();
  int wofs2 = 0;
  for (int ww = 0; ww < w; ++ww) wofs2 += wsum[ww];
  int nexcl = wofs2 + x - c;
  int v = (b << BSH) + t;
  if (t < NPB && v < N) {
    off[v] = wbase + nexcl;
    dinv[v] = rsqrtf((float)(c + 1));  // +1 self-loop
  }
  if (t < NPB) curL[t] = inLDS ? nexcl : (wbase + nexcl);
  if (b == B - 1 && t == 0) off[N] = E;
  __syncthreads();
  if (inLDS) {
#pragma unroll
    for (int g = 0; g < GPT; ++g) {
      int i = t + g * 256;
      if (i < total) {
        int p = atomicAdd(&curL[ev[g] & BMSK], 1);
        slot[p] = ev[g] >> BSH;
      }
    }
    __syncthreads();
    for (int i = t; i < total; i += 256) csr[wbase + i] = slot[i];
  } else {
    for (int k = t; k < nchunk; k += 256) {
      int base = rs[k], len = rl[k];
      for (int j = 0; j < len; ++j) {
        int e = packed[base + j];
        int p = atomicAdd(&curL[e & BMSK], 1);
        csr[p] = e >> BSH;
      }
    }
  }
}

// H'[v] = fp16((X @ W)[v] * dinv[v]).  Register-tile GEMM (R12, proven):
// block = 64 nodes x 64 features; thread = 4x4 tile; interleaved H rows.
__global__ __launch_bounds__(256) void k_gemm64t(const float* __restrict__ X,
                                                 const float* __restrict__ W,
                                                 const float* __restrict__ dinv,
                                                 __half* __restrict__ H, int N) {
  __shared__ float Wl[4096];   // [k][f]
  __shared__ float Xt[4096];   // [k][n] transposed tile
  int t = threadIdx.x;
  for (int i = t; i < 4096; i += 256) Wl[i] = W[i];
  int f0 = (t & 15) * 4;       // 4 features
  int ng = t >> 4;             // node group 0..15 -> nodes 4*ng..+3
  int sv = t & 63;             // staging: node within tile
  int sq = t >> 6;             // staging: k-quad -> k in [16*sq, 16*sq+16)
  int v0 = blockIdx.x * 64;
  bool valid = (v0 + sv) < N;
  const float4* Xr = (const float4*)(X + (size_t)(v0 + sv) * 64 + sq * 16);
  int kb = sq * 16;
#pragma unroll
  for (int c = 0; c < 4; ++c) {
    float4 xv = valid ? Xr[c] : make_float4(0.f, 0.f, 0.f, 0.f);
    Xt[(kb + 4 * c + 0) * 64 + sv] = xv.x;
    Xt[(kb + 4 * c + 1) * 64 + sv] = xv.y;
    Xt[(kb + 4 * c + 2) * 64 + sv] = xv.z;
    Xt[(kb + 4 * c + 3) * 64 + sv] = xv.w;
  }
  __syncthreads();
  float acc[4][4] = {};
#pragma unroll 16
  for (int k = 0; k < 64; ++k) {
    float4 wv = *(const float4*)&Wl[k * 64 + f0];
    float4 xv = *(const float4*)&Xt[k * 64 + 4 * ng];
    acc[0][0] = fmaf(xv.x, wv.x, acc[0][0]);
    acc[0][1] = fmaf(xv.x, wv.y, acc[0][1]);
    acc[0][2] = fmaf(xv.x, wv.z, acc[0][2]);
    acc[0][3] = fmaf(xv.x, wv.w, acc[0][3]);
    acc[1][0] = fmaf(xv.y, wv.x, acc[1][0]);
    acc[1][1] = fmaf(xv.y, wv.y, acc[1][1]);
    acc[1][2] = fmaf(xv.y, wv.z, acc[1][2]);
    acc[1][3] = fmaf(xv.y, wv.w, acc[1][3]);
    acc[2][0] = fmaf(xv.z, wv.x, acc[2][0]);
    acc[2][1] = fmaf(xv.z, wv.y, acc[2][1]);
    acc[2][2] = fmaf(xv.z, wv.z, acc[2][2]);
    acc[2][3] = fmaf(xv.z, wv.w, acc[2][3]);
    acc[3][0] = fmaf(xv.w, wv.x, acc[3][0]);
    acc[3][1] = fmaf(xv.w, wv.y, acc[3][1]);
    acc[3][2] = fmaf(xv.w, wv.z, acc[3][2]);
    acc[3][3] = fmaf(xv.w, wv.w, acc[3][3]);
  }
#pragma unroll
  for (int i = 0; i < 4; ++i) {
    int v = v0 + 4 * ng + i;
    if (v < N) {
      float dv = dinv[v];
      __half2 h01 = __floats2half2_rn(acc[i][0] * dv, acc[i][1] * dv);
      __half2 h23 = __floats2half2_rn(acc[i][2] * dv, acc[i][3] * dv);
      __half2* dst = (__half2*)(H + (size_t)v * 64 + f0);
      dst[0] = h01;
      dst[1] = h23;
    }
  }
}

__device__ __forceinline__ void acc8(float2 v, float2& a01, float2& a23) {
  const __half2* h = (const __half2*)&v;
  float2 f0 = __half22float2(h[0]);
  float2 f1 = __half22float2(h[1]);
  a01.x += f0.x; a01.y += f0.y;
  a23.x += f1.x; a23.y += f1.y;
}

__device__ __forceinline__ float2 ldrow(const char* Hc, int e, unsigned slb) {
  // 32-bit byte offset (max 100000*128 = 12.8MB): sgpr base + voffset form.
  return *(const float2*)(Hc + (((unsigned)e << 7) + slb));
}

// Pull aggregation, R14 version + R25 nontemporal streams: csr idx loads
// (single-use) and out stores (no reuse in this kernel) bypass L2 so H
// rows keep residency. Gather structure unchanged (proven 55.3us).
template <bool RELU>
__global__ __launch_bounds__(256) void k_agg(const __half* __restrict__ H,
                                             const int* __restrict__ csr,
                                             const int* __restrict__ off,
                                             const float* __restrict__ dinv,
                                             const float* __restrict__ bias,
                                             float* __restrict__ out, int N) {
  int wid = (blockIdx.x * blockDim.x + threadIdx.x) >> 6;
  int lane = threadIdx.x & 63;
  if (wid >= N) return;
  int sl = lane & 15;   // 8-byte slice of the 128B row (4 feats)
  int grp = lane >> 4;  // which of 4 concurrent edges
  unsigned slb = (unsigned)sl << 3;
  const char* Hc = (const char*)H;
  int beg = off[wid];
  int num = off[wid + 1] - beg;
  const int* cl = csr + beg;
  float2 a01 = make_float2(0.f, 0.f);
  float2 a23 = make_float2(0.f, 0.f);
  if (grp == 0) {  // self-loop term, counted once
    acc8(ldrow(Hc, wid, slb), a01, a23);
  }
  for (int base = 0; base < num; base += 64) {
    int navail = min(64, num - base);
    int sv = (base + lane < num) ? __builtin_nontemporal_load(cl + base + lane) : 0;
    int r = 0;
    for (; r + 32 <= navail; r += 32) {
      int eA = __shfl(sv, r + 0  + grp, 64);
      int eB = __shfl(sv, r + 4  + grp, 64);
      int eC = __shfl(sv, r + 8  + grp, 64);
      int eD = __shfl(sv, r + 12 + grp, 64);
      int eE = __shfl(sv, r + 16 + grp, 64);
      int eF = __shfl(sv, r + 20 + grp, 64);
      int eG = __shfl(sv, r + 24 + grp, 64);
      int eH = __shfl(sv, r + 28 + grp, 64);
      float2 fA = ldrow(Hc, eA, slb);
      float2 fB = ldrow(Hc, eB, slb);
      float2 fC = ldrow(Hc, eC, slb);
      float2 fD = ldrow(Hc, eD, slb);
      float2 fE = ldrow(Hc, eE, slb);
      float2 fF = ldrow(Hc, eF, slb);
      float2 fG = ldrow(Hc, eG, slb);
      float2 fH = ldrow(Hc, eH, slb);
      acc8(fA, a01, a23);
      acc8(fB, a01, a23);
      acc8(fC, a01, a23);
      acc8(fD, a01, a23);
      acc8(fE, a01, a23);
      acc8(fF, a01, a23);
      acc8(fG, a01, a23);
      acc8(fH, a01, a23);
    }
    int rem = navail - r;   // 0..31, wave-uniform
    if (rem & 16) {
      int eA = __shfl(sv, r + 0  + grp, 64);
      int eB = __shfl(sv, r + 4  + grp, 64);
      int eC = __shfl(sv, r + 8  + grp, 64);
      int eD = __shfl(sv, r + 12 + grp, 64);
      float2 fA = ldrow(Hc, eA, slb);
      float2 fB = ldrow(Hc, eB, slb);
      float2 fC = ldrow(Hc, eC, slb);
      float2 fD = ldrow(Hc, eD, slb);
      acc8(fA, a01, a23);
      acc8(fB, a01, a23);
      acc8(fC, a01, a23);
      acc8(fD, a01, a23);
      r += 16;
    }
    if (rem & 8) {
      int eA = __shfl(sv, r + 0 + grp, 64);
      int eB = __shfl(sv, r + 4 + grp, 64);
      float2 fA = ldrow(Hc, eA, slb);
      float2 fB = ldrow(Hc, eB, slb);
      acc8(fA, a01, a23);
      acc8(fB, a01, a23);
      r += 8;
    }
    if (rem & 4) {
      int eA = __shfl(sv, r + grp, 64);
      float2 fA = ldrow(Hc, eA, slb);
      acc8(fA, a01, a23);
      r += 4;
    }
    int last = rem & 3;
    if (last) {
      int e = __shfl(sv, (r + grp) & 63, 64);
      if (grp < last) {
        float2 f = ldrow(Hc, e, slb);
        acc8(f, a01, a23);
      }
    }
  }
  // reduce the 4 edge-group partials per slice
  a01.x += __shfl_xor(a01.x, 16);
  a01.y += __shfl_xor(a01.y, 16);
  a23.x += __shfl_xor(a23.x, 16);
  a23.y += __shfl_xor(a23.y, 16);
  a01.x += __shfl_xor(a01.x, 32);
  a01.y += __shfl_xor(a01.y, 32);
  a23.x += __shfl_xor(a23.x, 32);
  a23.y += __shfl_xor(a23.y, 32);
  if (grp == 0) {
    float dv = dinv[wid];
    float4 bb = ((const float4*)bias)[sl];
    nfloat4 r;
    r.x = fmaf(a01.x, dv, bb.x);
    r.y = fmaf(a01.y, dv, bb.y);
    r.z = fmaf(a23.x, dv, bb.z);
    r.w = fmaf(a23.y, dv, bb.w);
    if (RELU) {
      r.x = fmaxf(r.x, 0.f);
      r.y = fmaxf(r.y, 0.f);
      r.z = fmaxf(r.z, 0.f);
      r.w = fmaxf(r.w, 0.f);
    }
    __builtin_nontemporal_store(r, (nfloat4*)(out + (size_t)wid * 64) + sl);
  }
}

extern "C" void kernel_launch(void* const* d_in, const int* in_sizes, int n_in,
                              void* d_out, int out_size, void* d_ws, size_t ws_size,
                              hipStream_t stream) {
  const float* x  = (const float*)d_in[0];
  const float* W1 = (const float*)d_in[1];
  const float* b1 = (const float*)d_in[2];
  const float* W2 = (const float*)d_in[3];
  const float* b2 = (const float*)d_in[4];
  const int*   e0 = (const int*)d_in[5];
  const int*   e1 = (const int*)d_in[6];
  float* out = (float*)d_out;

  const int N = in_sizes[0] / 64;      // 100000
  const int E = in_sizes[5] / 2;       // 3200000
  const int B = (N + NPB - 1) / NPB;   // 782
  const int nchunk = (E + CHUNK - 1) / CHUNK;  // 391
  const int* srcL[2] = {e0, e1};       // dst = src + E

  // per-set sizes
  const size_t szrun  = (size_t)MAXCH * ROST * 4;
  const size_t szoff  = (size_t)(N + 1) * 4;
  const size_t szdinv = (size_t)N * 4;
  const size_t szpk   = (size_t)nchunk * CHUNK * 4;
  const size_t szcsr  = (size_t)E * 4;
  const size_t szH    = (size_t)N * 64 * 2;
  auto al = [](size_t v) { return (v + 255) & ~(size_t)255; };
  const size_t perset = al(szrun) + al(szoff) + al(szdinv) + al(szpk) + al(szcsr);
  const bool merged = (2 * perset + al(szH)) <= ws_size;
  const int nset = merged ? 2 : 1;

  char* w = (char*)d_ws;
  size_t o = 0;
  auto carve = [&](size_t bytes) -> void* {
    void* p = w + o;
    o = (o + bytes + 255) & ~(size_t)255;
    return p;
  };
  int* runS[2]; int* offS[2]; float* dinvS[2]; int* pkS[2]; int* csrS[2];
  for (int s = 0; s < nset; ++s) {
    runS[s] = (int*)carve(szrun);
    offS[s] = (int*)carve(szoff);
    dinvS[s] = (float*)carve(szdinv);
    pkS[s] = (int*)carve(szpk);
    csrS[s] = (int*)carve(szcsr);
  }
  __half* H = (__half*)carve(szH);
  if (!merged) {
    runS[1] = runS[0]; offS[1] = offS[0]; dinvS[1] = dinvS[0];
    pkS[1] = pkS[0]; csrS[1] = csrS[0];
  }

  const int aggblk = (N * 64 + 255) / 256;   // 25000
  const int gemmblk = (N + 63) / 64;         // 1563

  if (merged) {
    // both layers' graph preprocessing up front, double-width grids
    k_scatter<<<dim3(nchunk, 2), 256, 0, stream>>>(
        srcL[0], srcL[0] + E, runS[0], pkS[0],
        srcL[1], srcL[1] + E, runS[1], pkS[1], E, B);
    k_bfin4<<<dim3(B, 2), 256, 0, stream>>>(
        pkS[0], runS[0], offS[0], dinvS[0], csrS[0],
        pkS[1], runS[1], offS[1], dinvS[1], csrS[1], N, B, nchunk, E);
    k_gemm64t<<<gemmblk, 256, 0, stream>>>(x, W1, dinvS[0], H, N);
    k_agg<true><<<aggblk, 256, 0, stream>>>(H, csrS[0], offS[0], dinvS[0], b1, out, N);
    k_gemm64t<<<gemmblk, 256, 0, stream>>>(out, W2, dinvS[1], H, N);
    k_agg<false><<<aggblk, 256, 0, stream>>>(H, csrS[1], offS[1], dinvS[1], b2, out, N);
  } else {
    // serialized fallback (single buffer set)
    auto prep = [&](int l) {
      k_scatter<<<dim3(nchunk, 1), 256, 0, stream>>>(
          srcL[l], srcL[l] + E, runS[0], pkS[0],
          srcL[l], srcL[l] + E, runS[0], pkS[0], E, B);
      k_bfin4<<<dim3(B, 1), 256, 0, stream>>>(
          pkS[0], runS[0], offS[0], dinvS[0], csrS[0],
          pkS[0], runS[0], offS[0], dinvS[0], csrS[0], N, B, nchunk, E);
    };
    prep(0);
    k_gemm64t<<<gemmblk, 256, 0, stream>>>(x, W1, dinvS[0], H, N);
    k_agg<true><<<aggblk, 256, 0, stream>>>(H, csrS[0], offS[0], dinvS[0], b1, out, N);
    prep(1);
    k_gemm64t<<<gemmblk, 256, 0, stream>>>(out, W2, dinvS[0], H, N);
    k_agg<false><<<aggblk, 256, 0, stream>>>(H, csrS[0], offS[0], dinvS[0], b2, out, N);
  }
}

// Round 18
// 302.317 us; speedup vs baseline: 1.0122x; 1.0122x over previous
//
#include <hip/hip_runtime.h>
#include <hip/hip_fp16.h>

// 2-layer GCN: out = gcn(relu(gcn(x,W1,b1,e0)), W2, b2, e1)
// FINAL STATE (R27 = R24/R22 config, proven 303.5us best).
// Session summary (359.7 -> ~303.5):
//   R13: merged dual-layer preprocessing (grid.y=layer), -24us.
//   R14: agg = 16 lanes/edge x float2, coalesced 64-idx load + shfl,
//        8-gather/32-edge rounds, 16/8/4 ladder: 74.7->55.3us. FLOOR:
//        85% BW-bound on L2-miss path (FETCH 160MB @3.4TB/s).
//   R16: bfin4 stage[] removed (regs carry edges), occupancy 3->5
//        blocks/CU: only -2.8us -> prep is DS-issue-bound, not
//        occupancy-bound.
//   R19/R20: k_bsum + k_transpose DELETED via identities (run[k][0]=0
//        => wbase = column-sum of s; runoff[k][b],runoff[k][b+1]
//        adjacent). 8->6 launches.
//   R21/R22: CHUNK 8192 (half the packed-gather over-fetch): -6us.
//   CLOSED THEORIES (counter-verified dead ends):
//   - slab-agg (R17/18/23): FETCH 160->54MB confirmed, but payload
//     slicing x4 round count -> net +30..77us. CONDEMNED.
//   - predicated tail (R15): +12% requests at request ceiling.
//   - nt-hint streams (R25/26): FETCH -3%, time +2%: H hit rate is
//     CAPACITY-limited (12.8MB vs 4MiB/XCD L2), not pollution.
//   Remaining budget: agg 2x56 (BW floor), prep ~155 (DS-issue),
//   gemm ~16 (FLOP floor), gaps ~15. ROOFLINE.

#define NPB   128
#define BSH   7
#define BMSK  127
#define MAXB  1024          // >= B = ceil(100000/128) = 782
#define ROST  (MAXB + 1)    // runoff row stride
#define CHUNK 8192
#define EPTH  32            // edges per thread = CHUNK/256
#define MAXCH 512           // >= nchunk = ceil(E/CHUNK) = 391
#define BCAP  5120          // bucket cap (mean 4096, sd 64 -> +16sd)
#define GPT   20            // gather regs per thread = BCAP/256

// Sort chunk k by dst-bucket; edge data held in REGISTERS between passes.
// Dual-set: blockIdx.y selects layer (A=0, B=1).
__global__ __launch_bounds__(256) void k_scatter(const int* srcA, const int* dstA,
                                                 int* runA, int* pkA,
                                                 const int* srcB, const int* dstB,
                                                 int* runB, int* pkB,
                                                 int E, int B) {
  const int* src = blockIdx.y ? srcB : srcA;
  const int* dst = blockIdx.y ? dstB : dstA;
  int* runoff = blockIdx.y ? runB : runA;
  int* packed = blockIdx.y ? pkB : pkA;
  __shared__ int sorted[CHUNK];
  __shared__ int hist[MAXB];
  __shared__ int wsum[4];
  int t = threadIdx.x;
  int k = blockIdx.x;
  int e0 = k * CHUNK;
  int cnt = min(CHUNK, E - e0);
  for (int b = t; b < B; b += 256) hist[b] = 0;
  __syncthreads();
  int pk[EPTH];
  int bk[EPTH];
  int base = t * EPTH;
  int nloc = min(EPTH, max(0, cnt - base));
  if (cnt == CHUNK) {
    const int4* s4 = (const int4*)(src + e0 + base);
    const int4* d4 = (const int4*)(dst + e0 + base);
#pragma unroll
    for (int g = 0; g < EPTH / 4; ++g) {
      int4 sv = s4[g];
      int4 dv = d4[g];
      pk[4 * g + 0] = (sv.x << BSH) | (dv.x & BMSK); bk[4 * g + 0] = dv.x >> BSH;
      pk[4 * g + 1] = (sv.y << BSH) | (dv.y & BMSK); bk[4 * g + 1] = dv.y >> BSH;
      pk[4 * g + 2] = (sv.z << BSH) | (dv.z & BMSK); bk[4 * g + 2] = dv.z >> BSH;
      pk[4 * g + 3] = (sv.w << BSH) | (dv.w & BMSK); bk[4 * g + 3] = dv.w >> BSH;
      atomicAdd(&hist[bk[4 * g + 0]], 1);
      atomicAdd(&hist[bk[4 * g + 1]], 1);
      atomicAdd(&hist[bk[4 * g + 2]], 1);
      atomicAdd(&hist[bk[4 * g + 3]], 1);
    }
  } else {
    for (int q = 0; q < nloc; ++q) {
      int d = dst[e0 + base + q], s = src[e0 + base + q];
      pk[q] = (s << BSH) | (d & BMSK);
      bk[q] = d >> BSH;
      atomicAdd(&hist[bk[q]], 1);
    }
  }
  __syncthreads();
  int i0 = t * 4;
  int v0 = (i0 + 0 < B) ? hist[i0 + 0] : 0;
  int v1 = (i0 + 1 < B) ? hist[i0 + 1] : 0;
  int v2 = (i0 + 2 < B) ? hist[i0 + 2] : 0;
  int v3 = (i0 + 3 < B) ? hist[i0 + 3] : 0;
  int tsum = v0 + v1 + v2 + v3;
  int lane = t & 63, wid = t >> 6;
  int x = tsum;
#pragma unroll
  for (int d = 1; d < 64; d <<= 1) {
    int y = __shfl_up(x, d, 64);
    if (lane >= d) x += y;
  }
  if (lane == 63) wsum[wid] = x;
  __syncthreads();
  int wofs = 0;
  for (int ww = 0; ww < wid; ++ww) wofs += wsum[ww];
  int excl = wofs + x - tsum;
  hist[i0 + 0] = excl;
  hist[i0 + 1] = excl + v0;
  hist[i0 + 2] = excl + v0 + v1;
  hist[i0 + 3] = excl + v0 + v1 + v2;
  __syncthreads();
  int* row = runoff + (size_t)k * ROST;
  for (int b = t; b < B; b += 256) row[b] = hist[b];
  if (t == 0) row[B] = cnt;
  __syncthreads();
#pragma unroll
  for (int q = 0; q < EPTH; ++q) {
    if (q < nloc) {
      int pos = atomicAdd(&hist[bk[q]], 1);
      sorted[pos] = pk[q];
    }
  }
  __syncthreads();
  if (cnt == CHUNK) {
    int4* po = (int4*)(packed + e0 + base);
    const int4* so = (const int4*)(sorted + base);
#pragma unroll
    for (int g = 0; g < EPTH / 4; ++g) po[g] = so[g];
  } else {
    for (int i = t; i < cnt; i += 256) packed[e0 + i] = sorted[i];
  }
}

// Per-bucket finalize. Reads runoff directly (R20); wbase = column-sum
// of s (R19 identity); registers carry edges between passes (R16);
// guarded pref stores (R22).
__global__ __launch_bounds__(256) void k_bfin4(const int* pkA, const int* runA,
                                               int* offA, float* dinvA, int* csrA,
                                               const int* pkB, const int* runB,
                                               int* offB, float* dinvB, int* csrB,
                                               int N, int B, int nchunk, int E) {
  int l = blockIdx.y;
  const int* packed = l ? pkB : pkA;
  const int* runoff = l ? runB : runA;
  int* off = l ? offB : offA;
  float* dinv = l ? dinvB : dinvA;
  int* csr = l ? csrB : csrA;
  __shared__ int rs[MAXCH];
  __shared__ unsigned short rl[MAXCH];
  __shared__ int pref[MAXCH];
  __shared__ int slot[BCAP];
  __shared__ int cntL[NPB];
  __shared__ int curL[NPB];
  __shared__ int wsum[4];
  __shared__ int rsum[4];
  int t = threadIdx.x;
  int b = blockIdx.x;
  int lane = t & 63, w = t >> 6;
  int psS = 0;  // partial column-sum of s-values -> wbase
  for (int k = t; k < nchunk; k += 256) {
    const int* row = runoff + (size_t)k * ROST + b;
    int s = row[0];
    int e = row[1];
    rs[k] = k * CHUNK + s;
    rl[k] = (unsigned short)(e - s);
    psS += s;
  }
  if (t < NPB) cntL[t] = 0;
#pragma unroll
  for (int d = 32; d >= 1; d >>= 1) psS += __shfl_down(psS, d, 64);
  if (lane == 0) rsum[w] = psS;
  __syncthreads();
  int wbase = rsum[0] + rsum[1] + rsum[2] + rsum[3];
  int i0 = t * 4;
  int v0 = (i0 + 0 < nchunk) ? rl[i0 + 0] : 0;
  int v1 = (i0 + 1 < nchunk) ? rl[i0 + 1] : 0;
  int v2 = (i0 + 2 < nchunk) ? rl[i0 + 2] : 0;
  int v3 = (i0 + 3 < nchunk) ? rl[i0 + 3] : 0;
  int tsum = v0 + v1 + v2 + v3;
  int x = tsum;
#pragma unroll
  for (int d = 1; d < 64; d <<= 1) {
    int y = __shfl_up(x, d, 64);
    if (lane >= d) x += y;
  }
  if (lane == 63) wsum[w] = x;
  __syncthreads();
  int total = wsum[0] + wsum[1] + wsum[2] + wsum[3];
  int wofs = 0;
  for (int ww = 0; ww < w; ++ww) wofs += wsum[ww];
  int excl = wofs + x - tsum;
  if (i0 < MAXCH) {  // R22 fix: guard LDS stores
    pref[i0 + 0] = excl;
    pref[i0 + 1] = excl + v0;
    pref[i0 + 2] = excl + v0 + v1;
    pref[i0 + 3] = excl + v0 + v1 + v2;
  }
  __syncthreads();
  bool inLDS = (total <= BCAP);
  int ev[GPT];
  if (inLDS) {
    for (int k = t; k < nchunk; k += 256) {
      int base = rs[k], len = rl[k], o = pref[k];
      for (int j = 0; j < len; ++j) slot[o + j] = base + j;
    }
    __syncthreads();
    int av[GPT];
#pragma unroll
    for (int g = 0; g < GPT; ++g) {
      int i = t + g * 256;
      av[g] = (i < total) ? slot[i] : -1;
    }
#pragma unroll
    for (int g = 0; g < GPT; ++g) ev[g] = (av[g] >= 0) ? packed[av[g]] : 0;
#pragma unroll
    for (int g = 0; g < GPT; ++g) {
      int i = t + g * 256;
      if (i < total) atomicAdd(&cntL[ev[g] & BMSK], 1);
    }
  } else {
    for (int k = t; k < nchunk; k += 256) {
      int base = rs[k], len = rl[k];
      for (int j = 0; j < len; ++j)
        atomicAdd(&cntL[packed[base + j] & BMSK], 1);
    }
  }
  __syncthreads();
  int c = (t < NPB) ? cntL[t] : 0;
  x = c;
#pragma unroll
  for (int d = 1; d < 64; d <<= 1) {
    int y = __shfl_up(x, d, 64);
    if (lane >= d) x += y;
  }
  if (lane == 63) wsum[w] = x;
  __syncthreads();
  int wofs2 = 0;
  for (int ww = 0; ww < w; ++ww) wofs2 += wsum[ww];
  int nexcl = wofs2 + x - c;
  int v = (b << BSH) + t;
  if (t < NPB && v < N) {
    off[v] = wbase + nexcl;
    dinv[v] = rsqrtf((float)(c + 1));  // +1 self-loop
  }
  if (t < NPB) curL[t] = inLDS ? nexcl : (wbase + nexcl);
  if (b == B - 1 && t == 0) off[N] = E;
  __syncthreads();
  if (inLDS) {
#pragma unroll
    for (int g = 0; g < GPT; ++g) {
      int i = t + g * 256;
      if (i < total) {
        int p = atomicAdd(&curL[ev[g] & BMSK], 1);
        slot[p] = ev[g] >> BSH;
      }
    }
    __syncthreads();
    for (int i = t; i < total; i += 256) csr[wbase + i] = slot[i];
  } else {
    for (int k = t; k < nchunk; k += 256) {
      int base = rs[k], len = rl[k];
      for (int j = 0; j < len; ++j) {
        int e = packed[base + j];
        int p = atomicAdd(&curL[e & BMSK], 1);
        csr[p] = e >> BSH;
      }
    }
  }
}

// H'[v] = fp16((X @ W)[v] * dinv[v]).  Register-tile GEMM (R12, proven):
// block = 64 nodes x 64 features; thread = 4x4 tile; interleaved H rows.
__global__ __launch_bounds__(256) void k_gemm64t(const float* __restrict__ X,
                                                 const float* __restrict__ W,
                                                 const float* __restrict__ dinv,
                                                 __half* __restrict__ H, int N) {
  __shared__ float Wl[4096];   // [k][f]
  __shared__ float Xt[4096];   // [k][n] transposed tile
  int t = threadIdx.x;
  for (int i = t; i < 4096; i += 256) Wl[i] = W[i];
  int f0 = (t & 15) * 4;       // 4 features
  int ng = t >> 4;             // node group 0..15 -> nodes 4*ng..+3
  int sv = t & 63;             // staging: node within tile
  int sq = t >> 6;             // staging: k-quad -> k in [16*sq, 16*sq+16)
  int v0 = blockIdx.x * 64;
  bool valid = (v0 + sv) < N;
  const float4* Xr = (const float4*)(X + (size_t)(v0 + sv) * 64 + sq * 16);
  int kb = sq * 16;
#pragma unroll
  for (int c = 0; c < 4; ++c) {
    float4 xv = valid ? Xr[c] : make_float4(0.f, 0.f, 0.f, 0.f);
    Xt[(kb + 4 * c + 0) * 64 + sv] = xv.x;
    Xt[(kb + 4 * c + 1) * 64 + sv] = xv.y;
    Xt[(kb + 4 * c + 2) * 64 + sv] = xv.z;
    Xt[(kb + 4 * c + 3) * 64 + sv] = xv.w;
  }
  __syncthreads();
  float acc[4][4] = {};
#pragma unroll 16
  for (int k = 0; k < 64; ++k) {
    float4 wv = *(const float4*)&Wl[k * 64 + f0];
    float4 xv = *(const float4*)&Xt[k * 64 + 4 * ng];
    acc[0][0] = fmaf(xv.x, wv.x, acc[0][0]);
    acc[0][1] = fmaf(xv.x, wv.y, acc[0][1]);
    acc[0][2] = fmaf(xv.x, wv.z, acc[0][2]);
    acc[0][3] = fmaf(xv.x, wv.w, acc[0][3]);
    acc[1][0] = fmaf(xv.y, wv.x, acc[1][0]);
    acc[1][1] = fmaf(xv.y, wv.y, acc[1][1]);
    acc[1][2] = fmaf(xv.y, wv.z, acc[1][2]);
    acc[1][3] = fmaf(xv.y, wv.w, acc[1][3]);
    acc[2][0] = fmaf(xv.z, wv.x, acc[2][0]);
    acc[2][1] = fmaf(xv.z, wv.y, acc[2][1]);
    acc[2][2] = fmaf(xv.z, wv.z, acc[2][2]);
    acc[2][3] = fmaf(xv.z, wv.w, acc[2][3]);
    acc[3][0] = fmaf(xv.w, wv.x, acc[3][0]);
    acc[3][1] = fmaf(xv.w, wv.y, acc[3][1]);
    acc[3][2] = fmaf(xv.w, wv.z, acc[3][2]);
    acc[3][3] = fmaf(xv.w, wv.w, acc[3][3]);
  }
#pragma unroll
  for (int i = 0; i < 4; ++i) {
    int v = v0 + 4 * ng + i;
    if (v < N) {
      float dv = dinv[v];
      __half2 h01 = __floats2half2_rn(acc[i][0] * dv, acc[i][1] * dv);
      __half2 h23 = __floats2half2_rn(acc[i][2] * dv, acc[i][3] * dv);
      __half2* dst = (__half2*)(H + (size_t)v * 64 + f0);
      dst[0] = h01;
      dst[1] = h23;
    }
  }
}

__device__ __forceinline__ void acc8(float2 v, float2& a01, float2& a23) {
  const __half2* h = (const __half2*)&v;
  float2 f0 = __half22float2(h[0]);
  float2 f1 = __half22float2(h[1]);
  a01.x += f0.x; a01.y += f0.y;
  a23.x += f1.x; a23.y += f1.y;
}

__device__ __forceinline__ float2 ldrow(const char* Hc, int e, unsigned slb) {
  // 32-bit byte offset (max 100000*128 = 12.8MB): sgpr base + voffset form.
  return *(const float2*)(Hc + (((unsigned)e << 7) + slb));
}

// Pull aggregation, R14 version (proven 55.3us): 16 lanes/edge (8B float2
// slice), coalesced 64-idx load + shfl broadcast, 8-gather/32-edge main
// rounds, 16/8/4 ladder + masked last, single cross-group reduce per node.
template <bool RELU>
__global__ __launch_bounds__(256) void k_agg(const __half* __restrict__ H,
                                             const int* __restrict__ csr,
                                             const int* __restrict__ off,
                                             const float* __restrict__ dinv,
                                             const float* __restrict__ bias,
                                             float* __restrict__ out, int N) {
  int wid = (blockIdx.x * blockDim.x + threadIdx.x) >> 6;
  int lane = threadIdx.x & 63;
  if (wid >= N) return;
  int sl = lane & 15;   // 8-byte slice of the 128B row (4 feats)
  int grp = lane >> 4;  // which of 4 concurrent edges
  unsigned slb = (unsigned)sl << 3;
  const char* Hc = (const char*)H;
  int beg = off[wid];
  int num = off[wid + 1] - beg;
  const int* cl = csr + beg;
  float2 a01 = make_float2(0.f, 0.f);
  float2 a23 = make_float2(0.f, 0.f);
  if (grp == 0) {  // self-loop term, counted once
    acc8(ldrow(Hc, wid, slb), a01, a23);
  }
  for (int base = 0; base < num; base += 64) {
    int navail = min(64, num - base);
    int sv = (base + lane < num) ? cl[base + lane] : 0;
    int r = 0;
    for (; r + 32 <= navail; r += 32) {
      int eA = __shfl(sv, r + 0  + grp, 64);
      int eB = __shfl(sv, r + 4  + grp, 64);
      int eC = __shfl(sv, r + 8  + grp, 64);
      int eD = __shfl(sv, r + 12 + grp, 64);
      int eE = __shfl(sv, r + 16 + grp, 64);
      int eF = __shfl(sv, r + 20 + grp, 64);
      int eG = __shfl(sv, r + 24 + grp, 64);
      int eH = __shfl(sv, r + 28 + grp, 64);
      float2 fA = ldrow(Hc, eA, slb);
      float2 fB = ldrow(Hc, eB, slb);
      float2 fC = ldrow(Hc, eC, slb);
      float2 fD = ldrow(Hc, eD, slb);
      float2 fE = ldrow(Hc, eE, slb);
      float2 fF = ldrow(Hc, eF, slb);
      float2 fG = ldrow(Hc, eG, slb);
      float2 fH = ldrow(Hc, eH, slb);
      acc8(fA, a01, a23);
      acc8(fB, a01, a23);
      acc8(fC, a01, a23);
      acc8(fD, a01, a23);
      acc8(fE, a01, a23);
      acc8(fF, a01, a23);
      acc8(fG, a01, a23);
      acc8(fH, a01, a23);
    }
    int rem = navail - r;   // 0..31, wave-uniform
    if (rem & 16) {
      int eA = __shfl(sv, r + 0  + grp, 64);
      int eB = __shfl(sv, r + 4  + grp, 64);
      int eC = __shfl(sv, r + 8  + grp, 64);
      int eD = __shfl(sv, r + 12 + grp, 64);
      float2 fA = ldrow(Hc, eA, slb);
      float2 fB = ldrow(Hc, eB, slb);
      float2 fC = ldrow(Hc, eC, slb);
      float2 fD = ldrow(Hc, eD, slb);
      acc8(fA, a01, a23);
      acc8(fB, a01, a23);
      acc8(fC, a01, a23);
      acc8(fD, a01, a23);
      r += 16;
    }
    if (rem & 8) {
      int eA = __shfl(sv, r + 0 + grp, 64);
      int eB = __shfl(sv, r + 4 + grp, 64);
      float2 fA = ldrow(Hc, eA, slb);
      float2 fB = ldrow(Hc, eB, slb);
      acc8(fA, a01, a23);
      acc8(fB, a01, a23);
      r += 8;
    }
    if (rem & 4) {
      int eA = __shfl(sv, r + grp, 64);
      float2 fA = ldrow(Hc, eA, slb);
      acc8(fA, a01, a23);
      r += 4;
    }
    int last = rem & 3;
    if (last) {
      int e = __shfl(sv, (r + grp) & 63, 64);
      if (grp < last) {
        float2 f = ldrow(Hc, e, slb);
        acc8(f, a01, a23);
      }
    }
  }
  // reduce the 4 edge-group partials per slice
  a01.x += __shfl_xor(a01.x, 16);
  a01.y += __shfl_xor(a01.y, 16);
  a23.x += __shfl_xor(a23.x, 16);
  a23.y += __shfl_xor(a23.y, 16);
  a01.x += __shfl_xor(a01.x, 32);
  a01.y += __shfl_xor(a01.y, 32);
  a23.x += __shfl_xor(a23.x, 32);
  a23.y += __shfl_xor(a23.y, 32);
  if (grp == 0) {
    float dv = dinv[wid];
    float4 bb = ((const float4*)bias)[sl];
    float4 r;
    r.x = fmaf(a01.x, dv, bb.x);
    r.y = fmaf(a01.y, dv, bb.y);
    r.z = fmaf(a23.x, dv, bb.z);
    r.w = fmaf(a23.y, dv, bb.w);
    if (RELU) {
      r.x = fmaxf(r.x, 0.f);
      r.y = fmaxf(r.y, 0.f);
      r.z = fmaxf(r.z, 0.f);
      r.w = fmaxf(r.w, 0.f);
    }
    ((float4*)(out + (size_t)wid * 64))[sl] = r;
  }
}

extern "C" void kernel_launch(void* const* d_in, const int* in_sizes, int n_in,
                              void* d_out, int out_size, void* d_ws, size_t ws_size,
                              hipStream_t stream) {
  const float* x  = (const float*)d_in[0];
  const float* W1 = (const float*)d_in[1];
  const float* b1 = (const float*)d_in[2];
  const float* W2 = (const float*)d_in[3];
  const float* b2 = (const float*)d_in[4];
  const int*   e0 = (const int*)d_in[5];
  const int*   e1 = (const int*)d_in[6];
  float* out = (float*)d_out;

  const int N = in_sizes[0] / 64;      // 100000
  const int E = in_sizes[5] / 2;       // 3200000
  const int B = (N + NPB - 1) / NPB;   // 782
  const int nchunk = (E + CHUNK - 1) / CHUNK;  // 391
  const int* srcL[2] = {e0, e1};       // dst = src + E

  // per-set sizes
  const size_t szrun  = (size_t)MAXCH * ROST * 4;
  const size_t szoff  = (size_t)(N + 1) * 4;
  const size_t szdinv = (size_t)N * 4;
  const size_t szpk   = (size_t)nchunk * CHUNK * 4;
  const size_t szcsr  = (size_t)E * 4;
  const size_t szH    = (size_t)N * 64 * 2;
  auto al = [](size_t v) { return (v + 255) & ~(size_t)255; };
  const size_t perset = al(szrun) + al(szoff) + al(szdinv) + al(szpk) + al(szcsr);
  const bool merged = (2 * perset + al(szH)) <= ws_size;
  const int nset = merged ? 2 : 1;

  char* w = (char*)d_ws;
  size_t o = 0;
  auto carve = [&](size_t bytes) -> void* {
    void* p = w + o;
    o = (o + bytes + 255) & ~(size_t)255;
    return p;
  };
  int* runS[2]; int* offS[2]; float* dinvS[2]; int* pkS[2]; int* csrS[2];
  for (int s = 0; s < nset; ++s) {
    runS[s] = (int*)carve(szrun);
    offS[s] = (int*)carve(szoff);
    dinvS[s] = (float*)carve(szdinv);
    pkS[s] = (int*)carve(szpk);
    csrS[s] = (int*)carve(szcsr);
  }
  __half* H = (__half*)carve(szH);
  if (!merged) {
    runS[1] = runS[0]; offS[1] = offS[0]; dinvS[1] = dinvS[0];
    pkS[1] = pkS[0]; csrS[1] = csrS[0];
  }

  const int aggblk = (N * 64 + 255) / 256;   // 25000
  const int gemmblk = (N + 63) / 64;         // 1563

  if (merged) {
    // both layers' graph preprocessing up front, double-width grids
    k_scatter<<<dim3(nchunk, 2), 256, 0, stream>>>(
        srcL[0], srcL[0] + E, runS[0], pkS[0],
        srcL[1], srcL[1] + E, runS[1], pkS[1], E, B);
    k_bfin4<<<dim3(B, 2), 256, 0, stream>>>(
        pkS[0], runS[0], offS[0], dinvS[0], csrS[0],
        pkS[1], runS[1], offS[1], dinvS[1], csrS[1], N, B, nchunk, E);
    k_gemm64t<<<gemmblk, 256, 0, stream>>>(x, W1, dinvS[0], H, N);
    k_agg<true><<<aggblk, 256, 0, stream>>>(H, csrS[0], offS[0], dinvS[0], b1, out, N);
    k_gemm64t<<<gemmblk, 256, 0, stream>>>(out, W2, dinvS[1], H, N);
    k_agg<false><<<aggblk, 256, 0, stream>>>(H, csrS[1], offS[1], dinvS[1], b2, out, N);
  } else {
    // serialized fallback (single buffer set)
    auto prep = [&](int l) {
      k_scatter<<<dim3(nchunk, 1), 256, 0, stream>>>(
          srcL[l], srcL[l] + E, runS[0], pkS[0],
          srcL[l], srcL[l] + E, runS[0], pkS[0], E, B);
      k_bfin4<<<dim3(B, 1), 256, 0, stream>>>(
          pkS[0], runS[0], offS[0], dinvS[0], csrS[0],
          pkS[0], runS[0], offS[0], dinvS[0], csrS[0], N, B, nchunk, E);
    };
    prep(0);
    k_gemm64t<<<gemmblk, 256, 0, stream>>>(x, W1, dinvS[0], H, N);
    k_agg<true><<<aggblk, 256, 0, stream>>>(H, csrS[0], offS[0], dinvS[0], b1, out, N);
    prep(1);
    k_gemm64t<<<gemmblk, 256, 0, stream>>>(out, W2, dinvS[0], H, N);
    k_agg<false><<<aggblk, 256, 0, stream>>>(H, csrS[0], offS[0], dinvS[0], b2, out, N);
  }
}